// Round 16
// baseline (53.565 us; speedup 1.0000x reference)
//
#include <hip/hip_runtime.h>
#include <hip/hip_bf16.h>

typedef __attribute__((ext_vector_type(8))) short bf16x8;
typedef __attribute__((ext_vector_type(4))) float f32x4;

#define BATCH 16
#define SEQ   1024
#define EMB   768
#define HEAD  64
#define NT    (BATCH*SEQ)
#define NQKV  192
#define OSTR  104        // repack LDS row stride (ushorts): 208B, 16B-aligned

__device__ inline ushort f2bf(float f) {
  __hip_bfloat16 h = __float2bfloat16(f);
  return *reinterpret_cast<const ushort*>(&h);
}

__device__ inline void lds_dma16(const void* g, void* l) {
  __builtin_amdgcn_global_load_lds(
      (const __attribute__((address_space(1))) void*)g,
      (__attribute__((address_space(3))) void*)l, 16, 0, 0);
}

// ---------- W fp32 -> wt bf16 (pre-swizzled rows: chunk g stored at g^(row&7)) ----------
__global__ __launch_bounds__(256) void convw_kernel(
    const float* __restrict__ Wq, const float* __restrict__ Wk,
    const float* __restrict__ Wv, ushort* __restrict__ wt)
{
  const int row = blockIdx.x * 8 + (threadIdx.x >> 5);
  const float* W = (row < 64) ? Wq : (row < 128 ? Wk : Wv);
  const int r = row & 63;
  #pragma unroll
  for (int j = 0; j < 3; ++j) {
    const int c = (threadIdx.x & 31) + 32 * j;   // stored chunk 0..95
    const int grp = c >> 3, gst = c & 7;
    const int glog = gst ^ (row & 7);
    const int srccol = (grp << 6) + (glog << 3);
    const float4 f0 = *reinterpret_cast<const float4*>(&W[(size_t)r * EMB + srccol]);
    const float4 f1 = *reinterpret_cast<const float4*>(&W[(size_t)r * EMB + srccol + 4]);
    union { ushort us[8]; uint4 u; } o;
    o.us[0]=f2bf(f0.x); o.us[1]=f2bf(f0.y); o.us[2]=f2bf(f0.z); o.us[3]=f2bf(f0.w);
    o.us[4]=f2bf(f1.x); o.us[5]=f2bf(f1.y); o.us[6]=f2bf(f1.z); o.us[7]=f2bf(f1.w);
    *reinterpret_cast<uint4*>(&wt[(size_t)row * EMB + (c << 3)]) = o.u;
  }
}

// ---------- proj v6: weight-resident, zero-barrier K-loop ----------
// grid 256 = 128 M-tiles(128 rows) x 2 N-halves(96 cols). 512 thr = 8 waves.
// W-half (96x768 bf16, swizzled) staged ONCE in LDS (144 KB). A-frags direct
// from global x (fp32->bf16 in-reg). Wave (wr=wave>>1, wn=wave&1): rows
// wr*32..+31 (a[2]), cols wn*48..+47 (acc[2][3]).
__global__ __launch_bounds__(512) void proj_kernel(
    const float* __restrict__ x, const ushort* __restrict__ wt,
    ushort* __restrict__ qo, ushort* __restrict__ ko, ushort* __restrict__ vo)
{
  __shared__ ushort WL[96 * 768];      // 147456 B; epilogue reuses as [128][OSTR]

  const int tid  = threadIdx.x;
  const int wave = tid >> 6, lane = tid & 63;
  const int mb   = blockIdx.x >> 1, nb = blockIdx.x & 1;
  const int m0   = mb * 128;
  const int wr   = wave >> 1, wn = wave & 1;
  const int col16 = lane & 15, quad = lane >> 4;

  // ---- stage W-half once: flat 144 KB copy (18 x 512 lanes x 16B) ----
  {
    const ushort* wsrc = wt + (size_t)nb * 96 * EMB;
    #pragma unroll
    for (int it = 0; it < 18; ++it)
      lds_dma16(&wsrc[(size_t)(it * 512 + wave * 64 + lane) * 8],
                &WL[(it * 512 + wave * 64) * 8]);
  }

  // A-row base pointers (fp32): rows wr*32 + m*16 + col16
  const float* xr0 = &x[(size_t)(m0 + wr * 32 + col16) * EMB + quad * 8];
  const float* xr1 = xr0 + 16 * EMB;

  f32x4 acc[2][3];
  #pragma unroll
  for (int m = 0; m < 2; ++m)
    #pragma unroll
    for (int n = 0; n < 3; ++n) acc[m][n] = (f32x4){0.f, 0.f, 0.f, 0.f};

  __syncthreads();                     // W resident (vmcnt drained by barrier)

  #define PACK(dst_, A_, B_) {                                                  \
    union { ushort us[8]; bf16x8 v; } p_;                                       \
    p_.us[0]=f2bf((A_).x); p_.us[1]=f2bf((A_).y); p_.us[2]=f2bf((A_).z); p_.us[3]=f2bf((A_).w); \
    p_.us[4]=f2bf((B_).x); p_.us[5]=f2bf((B_).y); p_.us[6]=f2bf((B_).z); p_.us[7]=f2bf((B_).w); \
    dst_ = p_.v; }

  float4 c00 = *reinterpret_cast<const float4*>(xr0);
  float4 c01 = *reinterpret_cast<const float4*>(xr0 + 4);
  float4 c10 = *reinterpret_cast<const float4*>(xr1);
  float4 c11 = *reinterpret_cast<const float4*>(xr1 + 4);

  #pragma unroll
  for (int kc = 0; kc < 24; ++kc) {
    float4 n00, n01, n10, n11;
    if (kc < 23) {
      n00 = *reinterpret_cast<const float4*>(xr0 + (kc + 1) * 32);
      n01 = *reinterpret_cast<const float4*>(xr0 + (kc + 1) * 32 + 4);
      n10 = *reinterpret_cast<const float4*>(xr1 + (kc + 1) * 32);
      n11 = *reinterpret_cast<const float4*>(xr1 + (kc + 1) * 32 + 4);
    }
    bf16x8 a0, a1;
    PACK(a0, c00, c01);
    PACK(a1, c10, c11);
    #pragma unroll
    for (int n = 0; n < 3; ++n) {
      const int r = wn * 48 + n * 16 + col16;
      const bf16x8 b = *reinterpret_cast<const bf16x8*>(
          &WL[r * EMB + (kc >> 1) * 64 + (((((kc & 1) * 4) + quad) ^ (r & 7)) << 3)]);
      acc[0][n] = __builtin_amdgcn_mfma_f32_16x16x32_bf16(a0, b, acc[0][n], 0, 0, 0);
      acc[1][n] = __builtin_amdgcn_mfma_f32_16x16x32_bf16(a1, b, acc[1][n], 0, 0, 0);
    }
    c00 = n00; c01 = n01; c10 = n10; c11 = n11;
  }
  #undef PACK

  // ---- epilogue: repack 128x96 tile into LDS, coalesced uint4 stores ----
  __syncthreads();                     // all B-reads done; WL reusable
  #pragma unroll
  for (int m = 0; m < 2; ++m)
    #pragma unroll
    for (int n = 0; n < 3; ++n)
      #pragma unroll
      for (int i = 0; i < 4; ++i)
        WL[(wr * 32 + m * 16 + quad * 4 + i) * OSTR + wn * 48 + n * 16 + col16]
            = f2bf(acc[m][n][i]);
  __syncthreads();

  if (nb == 0) {
    // tile cols: 0..63 = q, 64..95 = k-lo (h 0..31)
    #pragma unroll
    for (int e = 0; e < 3; ++e) {
      const int slot = tid + 512 * e;            // 0..1535
      if (slot < 1024) {                         // q: 128 rows x 8 chunks
        const int rr = slot >> 3, g = slot & 7;
        *reinterpret_cast<uint4*>(&qo[(size_t)(m0 + rr) * HEAD + g * 8]) =
            *reinterpret_cast<const uint4*>(&WL[rr * OSTR + g * 8]);
      } else {                                   // k-lo: logical h-groups 0..3
        const int s2 = slot - 1024;
        const int rr = s2 >> 2, lg = s2 & 3;
        const int g = lg ^ (rr & 7);             // stored chunk position
        *reinterpret_cast<uint4*>(&ko[(size_t)(m0 + rr) * HEAD + g * 8]) =
            *reinterpret_cast<const uint4*>(&WL[rr * OSTR + 64 + lg * 8]);
      }
    }
  } else {
    // tile cols: 0..31 = k-hi (h 32..63), 32..95 = v (h 0..63)
    const int bb = m0 >> 10, tb = m0 & 1023;
    #pragma unroll
    for (int e = 0; e < 3; ++e) {
      const int slot = tid + 512 * e;            // 0..1535
      if (slot < 512) {                          // k-hi: logical h-groups 4..7
        const int rr = slot >> 2, l4 = slot & 3;
        const int hg = 4 + l4;
        const int g = hg ^ (rr & 7);
        *reinterpret_cast<uint4*>(&ko[(size_t)(m0 + rr) * HEAD + g * 8]) =
            *reinterpret_cast<const uint4*>(&WL[rr * OSTR + l4 * 8]);
      } else {                                   // vT: 64 h x 2 t-groups x 8 chunks
        const int s2 = slot - 512;               // 0..1023
        const int h  = s2 >> 4;
        const int gg = (s2 >> 3) & 1;
        const int g  = s2 & 7;
        union { ushort us[8]; uint4 u; } pv;
        #pragma unroll
        for (int ee = 0; ee < 8; ++ee) {
          const int lt = gg * 64 + ((g ^ (h & 7)) << 3) + ee;   // local t-row
          pv.us[ee] = WL[lt * OSTR + 32 + h];
        }
        *reinterpret_cast<uint4*>(
            &vo[((size_t)bb * HEAD + h) * SEQ + tb + gg * 64 + g * 8]) = pv.u;
      }
    }
  }
}

// ---------------- Flash attention v9 (frozen from R13) ----------------
__global__ __launch_bounds__(256) void attn_kernel(
    const ushort* __restrict__ q, const ushort* __restrict__ k,
    const ushort* __restrict__ vT, float* __restrict__ out,
    float* __restrict__ po, float* __restrict__ pl)
{
  __shared__ ushort Kl[2][64 * 64];     // 16 KB
  __shared__ ushort Vl[2][64 * 64];     // 16 KB
  __shared__ ushort lp[4][16][72];      // 9 KB per-wave P

  const int tid  = threadIdx.x;
  const int wave = tid >> 6, lane = tid & 63;
  const int bid  = blockIdx.x;
  const int b    = bid & 15;
  const int u    = bid >> 4;            // unit 0..43

  int j, s, ns;
  if (u < 4)       { j = u;                s = 0;           ns = 1; }
  else if (u < 12) { j = 4 + ((u - 4) >> 1);  s = (u - 4) & 1; ns = 2; }
  else             { j = 8 + ((u - 12) >> 2); s = (u - 12) & 3; ns = 4; }

  const int qt0 = j * 64;
  const int nt  = j + 1;
  const int t0  = (nt * s) / ns;
  const int t1  = (nt * (s + 1)) / ns;
  const float SC2 = 0.03608439182435161f * 1.4426950408889634f;  // 768^-0.5 * log2e

  const int col  = lane & 15;
  const int quad = lane >> 4;
  const int koff = quad * 8;

  const size_t qb = ((size_t)b * SEQ + qt0 + 16 * wave + col) * HEAD;
  const bf16x8 qa0 = *reinterpret_cast<const bf16x8*>(&q[qb + koff]);
  const bf16x8 qa1 = *reinterpret_cast<const bf16x8*>(&q[qb + koff + 32]);

  #define STAGE(t_, buf_) {                                                     \
    _Pragma("unroll")                                                           \
    for (int r = 0; r < 2; ++r)                                                 \
      lds_dma16(&k[((size_t)b * SEQ + (t_) * 64 + r * 32 + wave * 8 + (lane >> 3)) * HEAD + (lane & 7) * 8], \
                &Kl[buf_][(r * 32 + wave * 8) * 64]);                           \
    _Pragma("unroll")                                                           \
    for (int r = 0; r < 2; ++r)                                                 \
      lds_dma16(&vT[((size_t)b * HEAD + r * 32 + wave * 8 + (lane >> 3)) * SEQ + (t_) * 64 + (lane & 7) * 8], \
                &Vl[buf_][(r * 32 + wave * 8) * 64]);                           \
  }

  f32x4 o[4];
  #pragma unroll
  for (int hf = 0; hf < 4; ++hf) o[hf] = (f32x4){0.f, 0.f, 0.f, 0.f};
  float l_part[4];
  #pragma unroll
  for (int i = 0; i < 4; ++i) l_part[i] = 0.f;

  STAGE(t0, 0);

  for (int t = t0; t < t1; ++t) {
    const int cur = (t - t0) & 1;
    __syncthreads();                      // DMA of buf[cur] done; prev compute done
    if (t + 1 < t1) STAGE(t + 1, cur ^ 1);

    f32x4 sreg[4];
    #pragma unroll
    for (int f = 0; f < 4; ++f) {
      const int rowf = 16 * f + col;
      const bf16x8 kb0 = *reinterpret_cast<const bf16x8*>(
          &Kl[cur][rowf * 64 + ((quad ^ (rowf & 7)) << 3)]);
      const bf16x8 kb1 = *reinterpret_cast<const bf16x8*>(
          &Kl[cur][rowf * 64 + (((quad + 4) ^ (rowf & 7)) << 3)]);
      f32x4 z = (f32x4){0.f, 0.f, 0.f, 0.f};
      z       = __builtin_amdgcn_mfma_f32_16x16x32_bf16(qa0, kb0, z, 0, 0, 0);
      sreg[f] = __builtin_amdgcn_mfma_f32_16x16x32_bf16(qa1, kb1, z, 0, 0, 0);
    }

    const bool last = (t == nt - 1);
    #pragma unroll
    for (int f = 0; f < 4; ++f) {
      const int kvc = t * 64 + 16 * f + col;
      #pragma unroll
      for (int i = 0; i < 4; ++i) {
        float v = sreg[f][i];
        if (last && kvc > qt0 + 16 * wave + quad * 4 + i) v = -1e30f;
        const float p = exp2f(v * SC2);
        l_part[i] += p;
        lp[wave][quad * 4 + i][16 * f + col] = f2bf(p);
      }
    }

    #pragma unroll
    for (int ks = 0; ks < 2; ++ks) {
      const bf16x8 pa = *reinterpret_cast<const bf16x8*>(&lp[wave][col][ks * 32 + koff]);
      #pragma unroll
      for (int hf = 0; hf < 4; ++hf) {
        const int vrow = 16 * hf + col;
        const int g = ks * 4 + quad;
        const bf16x8 vb = *reinterpret_cast<const bf16x8*>(
            &Vl[cur][vrow * 64 + ((g ^ (vrow & 7)) << 3)]);
        o[hf] = __builtin_amdgcn_mfma_f32_16x16x32_bf16(pa, vb, o[hf], 0, 0, 0);
      }
    }
  }

  #pragma unroll
  for (int i = 0; i < 4; ++i) {
    #pragma unroll
    for (int d = 1; d < 16; d <<= 1) l_part[i] += __shfl_xor(l_part[i], d);
  }

  if (ns == 1) {
    #pragma unroll
    for (int i = 0; i < 4; ++i) {
      const float inv = 1.0f / l_part[i];
      const int tq = qt0 + 16 * wave + quad * 4 + i;
      #pragma unroll
      for (int hf = 0; hf < 4; ++hf)
        out[((size_t)b * SEQ + tq) * HEAD + 16 * hf + col] = o[hf][i] * inv;
    }
  } else {
    const int su = u - 4;                         // 0..39
    const int pidx = b * 40 + su;
    float* pob = &po[(size_t)pidx * 4096];
    #pragma unroll
    for (int i = 0; i < 4; ++i) {
      const int r = 16 * wave + quad * 4 + i;
      #pragma unroll
      for (int hf = 0; hf < 4; ++hf)
        pob[r * 64 + 16 * hf + col] = o[hf][i];
      if (col == 0) pl[pidx * 64 + r] = l_part[i];
    }
  }
  #undef STAGE
}

// ---------------- combine (frozen) ----------------
__global__ __launch_bounds__(256) void combine_kernel(
    const float* __restrict__ po, const float* __restrict__ pl,
    float* __restrict__ out)
{
  const int idx = blockIdx.x * 256 + threadIdx.x;   // 786432
  const int c = idx & 63;
  const int r = (idx >> 6) & 63;
  const int e = idx >> 12;                // 0..191
  const int jj = e % 12, b = e / 12;
  const int j = 4 + jj;
  const int su0 = (j < 8) ? (j - 4) * 2 : 8 + (j - 8) * 4;
  const int ns  = (j < 8) ? 2 : 4;
  float num = 0.f, den = 0.f;
  for (int s = 0; s < ns; ++s) {
    const int pidx = b * 40 + su0 + s;
    num += po[(size_t)pidx * 4096 + r * 64 + c];
    den += pl[pidx * 64 + r];
  }
  out[((size_t)b * SEQ + j * 64 + r) * HEAD + c] = num / den;
}

extern "C" void kernel_launch(void* const* d_in, const int* in_sizes, int n_in,
                              void* d_out, int out_size, void* d_ws, size_t ws_size,
                              hipStream_t stream) {
  const float* x  = (const float*)d_in[0];
  const float* Wq = (const float*)d_in[1];
  const float* Wk = (const float*)d_in[2];
  const float* Wv = (const float*)d_in[3];

  char* base = (char*)d_ws;
  ushort* qw  = (ushort*)(base);                        // [NT][64] bf16 linear   (2 MB)
  ushort* kw  = (ushort*)(base + (2u << 20));           // [NT][64] bf16 swizzled (2 MB)
  ushort* vTw = (ushort*)(base + (4u << 20));           // [B][64][1024] swizzled (2 MB)
  ushort* wtw = (ushort*)(base + (6u << 20));           // [192][768] swizzled    (288 KB)
  float*  po  = (float*) (base + (8u << 20));           // [16][40][4096] fp32    (10.5 MB)
  float*  pl  = (float*) (base + (20u << 20));          // [16][40][64] fp32      (164 KB)
  float*  out = (float*)d_out;

  convw_kernel<<<NQKV / 8, 256, 0, stream>>>(Wq, Wk, Wv, wtw);
  proj_kernel<<<256, 512, 0, stream>>>(x, wtw, qw, kw, vTw);
  attn_kernel<<<BATCH * 44, 256, 0, stream>>>(qw, kw, vTw, out, po, pl);
  combine_kernel<<<786432 / 256, 256, 0, stream>>>(po, pl, out);
}

// Round 17
// 45.488 us; speedup vs baseline: 1.1776x; 1.1776x over previous
//
#include <hip/hip_runtime.h>
#include <hip/hip_bf16.h>

typedef __attribute__((ext_vector_type(8))) short bf16x8;
typedef __attribute__((ext_vector_type(4))) float f32x4;

#define BATCH 16
#define SEQ   1024
#define EMB   768
#define HEAD  64
#define NT    (BATCH*SEQ)
#define NQKV  192
#define OSTR  104        // repack LDS row stride (ushorts)

__device__ inline ushort f2bf(float f) {
  __hip_bfloat16 h = __float2bfloat16(f);
  return *reinterpret_cast<const ushort*>(&h);
}

__device__ inline void lds_dma16(const void* g, void* l) {
  __builtin_amdgcn_global_load_lds(
      (const __attribute__((address_space(1))) void*)g,
      (__attribute__((address_space(3))) void*)l, 16, 0, 0);
}

// ---------- conv: x fp32 -> xbf bf16 (swizzled) AND W fp32 -> wt bf16 (swizzled) ----------
// blocks 0..2047: x rows (8/block). blocks 2048..2071: W rows (8/block).
// Swizzle: within each 64-col group, stored chunk c holds logical chunk c^(row&7).
__global__ __launch_bounds__(256) void conv_kernel(
    const float* __restrict__ x, const float* __restrict__ Wq,
    const float* __restrict__ Wk, const float* __restrict__ Wv,
    ushort* __restrict__ xbf, ushort* __restrict__ wt)
{
  if (blockIdx.x < 2048) {
    const int row = blockIdx.x * 8 + (threadIdx.x >> 5);
    #pragma unroll
    for (int j = 0; j < 3; ++j) {
      const int c = (threadIdx.x & 31) + 32 * j;          // stored chunk 0..95
      const int grp = c >> 3, gst = c & 7;
      const int glog = gst ^ (row & 7);
      const int srccol = (grp << 6) + (glog << 3);
      const float4 f0 = *reinterpret_cast<const float4*>(&x[(size_t)row * EMB + srccol]);
      const float4 f1 = *reinterpret_cast<const float4*>(&x[(size_t)row * EMB + srccol + 4]);
      union { ushort us[8]; uint4 u; } o;
      o.us[0]=f2bf(f0.x); o.us[1]=f2bf(f0.y); o.us[2]=f2bf(f0.z); o.us[3]=f2bf(f0.w);
      o.us[4]=f2bf(f1.x); o.us[5]=f2bf(f1.y); o.us[6]=f2bf(f1.z); o.us[7]=f2bf(f1.w);
      *reinterpret_cast<uint4*>(&xbf[(size_t)row * EMB + (c << 3)]) = o.u;
    }
  } else {
    const int row = (blockIdx.x - 2048) * 8 + (threadIdx.x >> 5);
    const float* W = (row < 64) ? Wq : (row < 128 ? Wk : Wv);
    const int r = row & 63;
    #pragma unroll
    for (int j = 0; j < 3; ++j) {
      const int c = (threadIdx.x & 31) + 32 * j;
      const int grp = c >> 3, gst = c & 7;
      const int glog = gst ^ (row & 7);
      const int srccol = (grp << 6) + (glog << 3);
      const float4 f0 = *reinterpret_cast<const float4*>(&W[(size_t)r * EMB + srccol]);
      const float4 f1 = *reinterpret_cast<const float4*>(&W[(size_t)r * EMB + srccol + 4]);
      union { ushort us[8]; uint4 u; } o;
      o.us[0]=f2bf(f0.x); o.us[1]=f2bf(f0.y); o.us[2]=f2bf(f0.z); o.us[3]=f2bf(f0.w);
      o.us[4]=f2bf(f1.x); o.us[5]=f2bf(f1.y); o.us[6]=f2bf(f1.z); o.us[7]=f2bf(f1.w);
      *reinterpret_cast<uint4*>(&wt[(size_t)row * EMB + (c << 3)]) = o.u;
    }
  }
}

// ---------- proj v3 (R6 measured ~10.7us): all-DMA, BM32/BN96, 4 blocks/CU ----------
// grid 1024 = 512 M-tiles(32) x 2 N-halves(96). 256 thr = 4 waves.
// Epilogue: LDS repack (reuses Wl[0]) -> coalesced uint4 stores; k/vT swizzled for attn.
__global__ __launch_bounds__(256) void proj_kernel(
    const ushort* __restrict__ xbf, const ushort* __restrict__ wt,
    ushort* __restrict__ qo, ushort* __restrict__ ko, ushort* __restrict__ vo)
{
  __shared__ ushort Xl[2][32 * 64];    // 8 KB
  __shared__ ushort Wl[2][96 * 64];    // 24 KB

  const int tid  = threadIdx.x;
  const int wave = tid >> 6, lane = tid & 63;
  const int mb   = blockIdx.x >> 1, nb = blockIdx.x & 1;
  const int m0   = mb * 32;
  const int nb96 = nb * 96;
  const int wr   = wave >> 1, wc = wave & 1;
  const int col16 = lane & 15, quad = lane >> 4;

  // DMA: 16 segs of 1KB (X:0-3, W:4-15); wave stages segs 4w..4w+3.
  #define STAGE(kt_, buf_) { _Pragma("unroll")                                  \
    for (int u5 = 0; u5 < 4; ++u5) {                                            \
      const int u = wave * 4 + u5;                                              \
      if (u < 4) {                                                              \
        lds_dma16(&xbf[(size_t)(m0 + u * 8 + (lane >> 3)) * EMB + (kt_) * 64 + (lane & 7) * 8], \
                  &Xl[buf_][u * 512]);                                          \
      } else {                                                                  \
        const int s = u - 4;                                                    \
        lds_dma16(&wt[(size_t)(nb96 + s * 8 + (lane >> 3)) * EMB + (kt_) * 64 + (lane & 7) * 8], \
                  &Wl[buf_][s * 512]);                                          \
      } } }

  f32x4 acc[3];
  #pragma unroll
  for (int n = 0; n < 3; ++n) acc[n] = (f32x4){0.f, 0.f, 0.f, 0.f};

  STAGE(0, 0);

  for (int kt = 0; kt < 12; ++kt) {
    const int cur = kt & 1;
    __syncthreads();                       // buf[cur] ready (vmcnt drained)
    if (kt < 11) STAGE(kt + 1, cur ^ 1);
    #pragma unroll
    for (int ks = 0; ks < 2; ++ks) {
      const int g = ks * 4 + quad;         // logical 16B chunk 0..7
      const int ar = wr * 16 + col16;
      const bf16x8 a = *reinterpret_cast<const bf16x8*>(
          &Xl[cur][ar * 64 + ((g ^ (ar & 7)) << 3)]);
      #pragma unroll
      for (int n = 0; n < 3; ++n) {
        const int br = wc * 48 + 16 * n + col16;
        const bf16x8 b = *reinterpret_cast<const bf16x8*>(
            &Wl[cur][br * 64 + ((g ^ (br & 7)) << 3)]);
        acc[n] = __builtin_amdgcn_mfma_f32_16x16x32_bf16(a, b, acc[n], 0, 0, 0);
      }
    }
  }

  // ---- epilogue: repack 32x96 tile into LDS, then coalesced uint4 stores ----
  __syncthreads();                         // all MFMA LDS reads done
  {
    ushort* RP = &Wl[0][0];                // 32*OSTR = 6656 B, fits in 12 KB
    const int tr = wr * 16 + quad * 4;     // +i
    #pragma unroll
    for (int n = 0; n < 3; ++n)
      #pragma unroll
      for (int i = 0; i < 4; ++i)
        RP[(tr + i) * OSTR + wc * 48 + n * 16 + col16] = f2bf(acc[n][i]);
    __syncthreads();

    if (nb == 0) {
      // tile cols 0..63 = q(h0-63); 64..95 = k(h0-31)
      {
        const int rr = tid >> 3, g = tid & 7;            // 256 q stores
        *reinterpret_cast<uint4*>(&qo[(size_t)(m0 + rr) * HEAD + g * 8]) =
            *reinterpret_cast<const uint4*>(&RP[rr * OSTR + g * 8]);
      }
      if (tid < 128) {                                   // k-lo: lg 0..3
        const int rr = tid >> 2, lg = tid & 3;
        const int c = lg ^ (rr & 7);                     // stored chunk
        *reinterpret_cast<uint4*>(&ko[(size_t)(m0 + rr) * HEAD + c * 8]) =
            *reinterpret_cast<const uint4*>(&RP[rr * OSTR + 64 + lg * 8]);
      }
    } else {
      // tile cols 0..31 = k(h32-63); 32..95 = v(h0-63)
      if (tid < 128) {                                   // k-hi: lg 4..7
        const int rr = tid >> 2, l4 = tid & 3;
        const int lg = 4 + l4;
        const int c = lg ^ (rr & 7);
        *reinterpret_cast<uint4*>(&ko[(size_t)(m0 + rr) * HEAD + c * 8]) =
            *reinterpret_cast<const uint4*>(&RP[rr * OSTR + l4 * 8]);
      }
      {                                                  // vT: 64 h x 4 o-groups
        const int h = tid >> 2, d = tid & 3;
        const int w = (m0 & 63) >> 3;                    // 0 or 4
        const int lg = w + d;                            // logical o-group in 64-tile
        const int c = lg ^ (h & 7);                      // stored chunk
        union { ushort us[8]; uint4 u; } pv;
        #pragma unroll
        for (int e = 0; e < 8; ++e)
          pv.us[e] = RP[(d * 8 + e) * OSTR + 32 + h];
        const int bb = m0 >> 10;
        const int tb64 = (m0 & 1023) & ~63;
        *reinterpret_cast<uint4*>(
            &vo[((size_t)bb * HEAD + h) * SEQ + tb64 + c * 8]) = pv.u;
      }
    }
  }
  #undef STAGE
}

// ---------------- Flash attention v9 (frozen from R13) ----------------
__global__ __launch_bounds__(256) void attn_kernel(
    const ushort* __restrict__ q, const ushort* __restrict__ k,
    const ushort* __restrict__ vT, float* __restrict__ out,
    float* __restrict__ po, float* __restrict__ pl)
{
  __shared__ ushort Kl[2][64 * 64];     // 16 KB
  __shared__ ushort Vl[2][64 * 64];     // 16 KB
  __shared__ ushort lp[4][16][72];      // 9 KB per-wave P

  const int tid  = threadIdx.x;
  const int wave = tid >> 6, lane = tid & 63;
  const int bid  = blockIdx.x;
  const int b    = bid & 15;
  const int u    = bid >> 4;            // unit 0..43

  int j, s, ns;
  if (u < 4)       { j = u;                s = 0;           ns = 1; }
  else if (u < 12) { j = 4 + ((u - 4) >> 1);  s = (u - 4) & 1; ns = 2; }
  else             { j = 8 + ((u - 12) >> 2); s = (u - 12) & 3; ns = 4; }

  const int qt0 = j * 64;
  const int nt  = j + 1;
  const int t0  = (nt * s) / ns;
  const int t1  = (nt * (s + 1)) / ns;
  const float SC2 = 0.03608439182435161f * 1.4426950408889634f;  // 768^-0.5 * log2e

  const int col  = lane & 15;
  const int quad = lane >> 4;
  const int koff = quad * 8;

  const size_t qb = ((size_t)b * SEQ + qt0 + 16 * wave + col) * HEAD;
  const bf16x8 qa0 = *reinterpret_cast<const bf16x8*>(&q[qb + koff]);
  const bf16x8 qa1 = *reinterpret_cast<const bf16x8*>(&q[qb + koff + 32]);

  #define STAGE(t_, buf_) {                                                     \
    _Pragma("unroll")                                                           \
    for (int r = 0; r < 2; ++r)                                                 \
      lds_dma16(&k[((size_t)b * SEQ + (t_) * 64 + r * 32 + wave * 8 + (lane >> 3)) * HEAD + (lane & 7) * 8], \
                &Kl[buf_][(r * 32 + wave * 8) * 64]);                           \
    _Pragma("unroll")                                                           \
    for (int r = 0; r < 2; ++r)                                                 \
      lds_dma16(&vT[((size_t)b * HEAD + r * 32 + wave * 8 + (lane >> 3)) * SEQ + (t_) * 64 + (lane & 7) * 8], \
                &Vl[buf_][(r * 32 + wave * 8) * 64]);                           \
  }

  f32x4 o[4];
  #pragma unroll
  for (int hf = 0; hf < 4; ++hf) o[hf] = (f32x4){0.f, 0.f, 0.f, 0.f};
  float l_part[4];
  #pragma unroll
  for (int i = 0; i < 4; ++i) l_part[i] = 0.f;

  STAGE(t0, 0);

  for (int t = t0; t < t1; ++t) {
    const int cur = (t - t0) & 1;
    __syncthreads();                      // DMA of buf[cur] done; prev compute done
    if (t + 1 < t1) STAGE(t + 1, cur ^ 1);

    f32x4 sreg[4];
    #pragma unroll
    for (int f = 0; f < 4; ++f) {
      const int rowf = 16 * f + col;
      const bf16x8 kb0 = *reinterpret_cast<const bf16x8*>(
          &Kl[cur][rowf * 64 + ((quad ^ (rowf & 7)) << 3)]);
      const bf16x8 kb1 = *reinterpret_cast<const bf16x8*>(
          &Kl[cur][rowf * 64 + (((quad + 4) ^ (rowf & 7)) << 3)]);
      f32x4 z = (f32x4){0.f, 0.f, 0.f, 0.f};
      z       = __builtin_amdgcn_mfma_f32_16x16x32_bf16(qa0, kb0, z, 0, 0, 0);
      sreg[f] = __builtin_amdgcn_mfma_f32_16x16x32_bf16(qa1, kb1, z, 0, 0, 0);
    }

    const bool last = (t == nt - 1);
    #pragma unroll
    for (int f = 0; f < 4; ++f) {
      const int kvc = t * 64 + 16 * f + col;
      #pragma unroll
      for (int i = 0; i < 4; ++i) {
        float v = sreg[f][i];
        if (last && kvc > qt0 + 16 * wave + quad * 4 + i) v = -1e30f;
        const float p = exp2f(v * SC2);
        l_part[i] += p;
        lp[wave][quad * 4 + i][16 * f + col] = f2bf(p);
      }
    }

    #pragma unroll
    for (int ks = 0; ks < 2; ++ks) {
      const bf16x8 pa = *reinterpret_cast<const bf16x8*>(&lp[wave][col][ks * 32 + koff]);
      #pragma unroll
      for (int hf = 0; hf < 4; ++hf) {
        const int vrow = 16 * hf + col;
        const int g = ks * 4 + quad;
        const bf16x8 vb = *reinterpret_cast<const bf16x8*>(
            &Vl[cur][vrow * 64 + ((g ^ (vrow & 7)) << 3)]);
        o[hf] = __builtin_amdgcn_mfma_f32_16x16x32_bf16(pa, vb, o[hf], 0, 0, 0);
      }
    }
  }

  #pragma unroll
  for (int i = 0; i < 4; ++i) {
    #pragma unroll
    for (int d = 1; d < 16; d <<= 1) l_part[i] += __shfl_xor(l_part[i], d);
  }

  if (ns == 1) {
    #pragma unroll
    for (int i = 0; i < 4; ++i) {
      const float inv = 1.0f / l_part[i];
      const int tq = qt0 + 16 * wave + quad * 4 + i;
      #pragma unroll
      for (int hf = 0; hf < 4; ++hf)
        out[((size_t)b * SEQ + tq) * HEAD + 16 * hf + col] = o[hf][i] * inv;
    }
  } else {
    const int su = u - 4;                         // 0..39
    const int pidx = b * 40 + su;
    float* pob = &po[(size_t)pidx * 4096];
    #pragma unroll
    for (int i = 0; i < 4; ++i) {
      const int r = 16 * wave + quad * 4 + i;
      #pragma unroll
      for (int hf = 0; hf < 4; ++hf)
        pob[r * 64 + 16 * hf + col] = o[hf][i];
      if (col == 0) pl[pidx * 64 + r] = l_part[i];
    }
  }
  #undef STAGE
}

// ---------------- combine (frozen) ----------------
__global__ __launch_bounds__(256) void combine_kernel(
    const float* __restrict__ po, const float* __restrict__ pl,
    float* __restrict__ out)
{
  const int idx = blockIdx.x * 256 + threadIdx.x;   // 786432
  const int c = idx & 63;
  const int r = (idx >> 6) & 63;
  const int e = idx >> 12;                // 0..191
  const int jj = e % 12, b = e / 12;
  const int j = 4 + jj;
  const int su0 = (j < 8) ? (j - 4) * 2 : 8 + (j - 8) * 4;
  const int ns  = (j < 8) ? 2 : 4;
  float num = 0.f, den = 0.f;
  for (int s = 0; s < ns; ++s) {
    const int pidx = b * 40 + su0 + s;
    num += po[(size_t)pidx * 4096 + r * 64 + c];
    den += pl[pidx * 64 + r];
  }
  out[((size_t)b * SEQ + j * 64 + r) * HEAD + c] = num / den;
}

extern "C" void kernel_launch(void* const* d_in, const int* in_sizes, int n_in,
                              void* d_out, int out_size, void* d_ws, size_t ws_size,
                              hipStream_t stream) {
  const float* x  = (const float*)d_in[0];
  const float* Wq = (const float*)d_in[1];
  const float* Wk = (const float*)d_in[2];
  const float* Wv = (const float*)d_in[3];

  char* base = (char*)d_ws;
  ushort* qw  = (ushort*)(base);                        // [NT][64] bf16 linear   (2 MB)
  ushort* kw  = (ushort*)(base + (2u << 20));           // [NT][64] bf16 swizzled (2 MB)
  ushort* vTw = (ushort*)(base + (4u << 20));           // [B][64][1024] swizzled (2 MB)
  ushort* wtw = (ushort*)(base + (6u << 20));           // [192][768] swizzled    (288 KB)
  ushort* xbf = (ushort*)(base + (7u << 20));           // [NT][768] bf16 swizzled (24 MB)
  float*  po  = (float*) (base + (32u << 20));          // [16][40][4096] fp32    (10.5 MB)
  float*  pl  = (float*) (base + (44u << 20));          // [16][40][64] fp32      (164 KB)
  float*  out = (float*)d_out;

  conv_kernel<<<2048 + NQKV / 8, 256, 0, stream>>>(x, Wq, Wk, Wv, xbf, wtw);
  proj_kernel<<<(NT / 32) * 2, 256, 0, stream>>>(xbf, wtw, qw, kw, vTw);
  attn_kernel<<<BATCH * 44, 256, 0, stream>>>(qw, kw, vTw, out, po, pl);
  combine_kernel<<<786432 / 256, 256, 0, stream>>>(po, pl, out);
}